// Round 3
// baseline (50.156 us; speedup 1.0000x reference)
//
#include <hip/hip_runtime.h>
#include <math.h>

#define DD   768
#define BB   32
#define NTP  256        // target pixels per batch (16x16)
#define NSP  1024       // search pixels per batch (32x32)
#define NT   (BB*NTP)   // 8192
#define NS   (BB*NSP)   // 32768
#define NCH  2          // D-chunks for dot kernel
#define CHD  (DD/NCH)   // 384
#define ECH  48         // E-chunks for prep
#define CHE  (DD/ECH)   // 16

// ws layout (floats); float4-aligned offsets
#define OFF_UP 0                      // uPart[ECH][DD]
#define OFF_VP (OFF_UP + ECH*DD)      // vPart[ECH][DD]
#define OFF_U  (OFF_VP + ECH*DD)      // U[DD] final
#define OFF_V  (OFF_U + DD)           // V[DD] final
#define OFF_K  (OFF_V + DD)           // K1, K2 (+pad to 16)
#define OFF_TR (OFF_K + 16)           // tgt R partials [NCH][NT]
#define OFF_TS (OFF_TR + NCH*NT)      // tgt S partials [NCH][NT]
#define OFF_SR (OFF_TS + NCH*NT)      // search R partials [NCH][NS]
#define OFF_SS (OFF_SR + NCH*NS)      // search S partials [NCH][NS]
// total ~ 239,120 floats ~= 0.96 MB

__global__ void k_prep(const float* __restrict__ w, const float* __restrict__ cb,
                       const float* __restrict__ gamma, const float* __restrict__ beta,
                       const float* __restrict__ mean, const float* __restrict__ var,
                       const float* __restrict__ fi, float* __restrict__ ws) {
    int bx = blockIdx.x;
    int t = threadIdx.x;
    if (bx < ECH) {
        __shared__ float wu[CHE], wv[CHE];
        if (t < CHE) {
            int e = bx * CHE + t;
            float inv = gamma[e] / sqrtf(var[e] + 1e-5f);
            wv[t] = inv;
            wu[t] = inv * fi[e];
        }
        __syncthreads();
        if (t < 192) {   // 192 float4 = 768 d columns
            const float4* w4 = (const float4*)w;
            float4 Ru = {0,0,0,0}, Rv = {0,0,0,0};
            #pragma unroll
            for (int j = 0; j < CHE; ++j) {
                float4 x = w4[(size_t)(bx * CHE + j) * 192 + t];
                float a = wu[j], b = wv[j];
                Ru.x += x.x * a; Ru.y += x.y * a; Ru.z += x.z * a; Ru.w += x.w * a;
                Rv.x += x.x * b; Rv.y += x.y * b; Rv.z += x.z * b; Rv.w += x.w * b;
            }
            *(float4*)(ws + OFF_UP + bx * DD + t * 4) = Ru;
            *(float4*)(ws + OFF_VP + bx * DD + t * 4) = Rv;
        }
    } else {
        // K1 = sum_e ((cb-mean)*inv + beta)*fi ; K2 = sum_e ((cb-mean)*inv + beta)
        __shared__ float r1[256], r2[256];
        float a1 = 0.f, a2 = 0.f;
        for (int e = t; e < DD; e += 256) {
            float inv = gamma[e] / sqrtf(var[e] + 1e-5f);
            float x = (cb[e] - mean[e]) * inv + beta[e];
            a1 += x * fi[e];
            a2 += x;
        }
        r1[t] = a1; r2[t] = a2;
        __syncthreads();
        for (int s = 128; s > 0; s >>= 1) {
            if (t < s) { r1[t] += r1[t + s]; r2[t] += r2[t + s]; }
            __syncthreads();
        }
        if (t == 0) { ws[OFF_K] = r1[0]; ws[OFF_K + 1] = r2[0]; }
    }
}

// finalize U[d], V[d] = sum over ECH partials. 6 blocks x 256.
__global__ void k_prep2(float* __restrict__ ws) {
    int bx = blockIdx.x;
    int d = (bx % 3) * 256 + threadIdx.x;
    int isV = bx / 3;
    int srcOff = isV ? OFF_VP : OFF_UP;
    int dstOff = isV ? OFF_V : OFF_U;
    float a = 0.f;
    #pragma unroll 8
    for (int ec = 0; ec < ECH; ++ec) a += ws[srcOff + ec * DD + d];
    ws[dstOff + d] = a;
}

// 320 blocks: 256 search (128 px-groups x 2 ch-chunks) + 64 target (32 x 2).
// Block: 256 px group x 384-channel chunk; wave w handles 96 channels;
// float4 over 4 px/lane; 4-way cross-wave reduce; write partial chunk.
__global__ void k_dots(const float* __restrict__ tf, const float* __restrict__ sf,
                       float* __restrict__ ws) {
    int bx = blockIdx.x;
    int lane = threadIdx.x & 63, wv = threadIdx.x >> 6;
    __shared__ float su[CHD], sv[CHD];
    int cc, grp; bool isT;
    if (bx < 256) { isT = false; cc = bx & 1; grp = bx >> 1; }     // grp in [0,128)
    else          { isT = true;  int u = bx - 256; cc = u & 1; grp = u >> 1; } // [0,32)
    int c0 = cc * CHD;
    for (int d = threadIdx.x; d < CHD; d += 256) {
        su[d] = ws[OFF_U + c0 + d];
        sv[d] = ws[OFF_V + c0 + d];
    }
    __syncthreads();

    const float4* bp;
    int strideF4;
    float4 *outR, *outS;
    if (!isT) {
        int b = grp >> 2, q = grp & 3;
        bp = (const float4*)(sf + ((size_t)b * DD + c0) * NSP + q * 256 + lane * 4);
        strideF4 = NSP / 4;
        outR = (float4*)(ws + OFF_SR + cc * NS + grp * 256 + lane * 4);
        outS = (float4*)(ws + OFF_SS + cc * NS + grp * 256 + lane * 4);
    } else {
        bp = (const float4*)(tf + ((size_t)grp * DD + c0) * NTP + lane * 4);
        strideF4 = NTP / 4;
        outR = (float4*)(ws + OFF_TR + cc * NT + grp * 256 + lane * 4);
        outS = (float4*)(ws + OFF_TS + cc * NT + grp * 256 + lane * 4);
    }
    int jbase = wv * 96;
    float4 R = {0,0,0,0}, S = {0,0,0,0};
    #pragma unroll 8
    for (int k = 0; k < 96; ++k) {
        int j = jbase + k;
        float4 v = bp[(size_t)j * strideF4];
        float u = su[j], vb = sv[j];
        R.x += v.x * u;  R.y += v.y * u;  R.z += v.z * u;  R.w += v.w * u;
        S.x += v.x * vb; S.y += v.y * vb; S.z += v.z * vb; S.w += v.w * vb;
    }
    __shared__ float4 redR[4][64], redS[4][64];
    redR[wv][lane] = R; redS[wv][lane] = S;
    __syncthreads();
    if (wv == 0) {
        float4 r = redR[0][lane], s = redS[0][lane];
        #pragma unroll
        for (int u = 1; u < 4; ++u) {
            float4 a = redR[u][lane], b = redS[u][lane];
            r.x += a.x; r.y += a.y; r.z += a.z; r.w += a.w;
            s.x += b.x; s.y += b.y; s.z += b.z; s.w += b.w;
        }
        *outR = r; *outS = s;
    }
}

// One block per batch: filter iterations (shfl reductions) then output.
__global__ void k_out(const float* __restrict__ mask, const float* __restrict__ ws,
                      float* __restrict__ out) {
    int b = blockIdx.x;
    int p = threadIdx.x;           // target pixel in 16x16
    int lane = p & 63, wv = p >> 6;
    int h = p >> 4, w = p & 15;
    float K1 = ws[OFF_K], K2 = ws[OFF_K + 1];
    float r0 = K1 + ws[OFF_TR + b * 256 + p] + ws[OFF_TR + NT + b * 256 + p];
    float s0 = K2 + ws[OFF_TS + b * 256 + p] + ws[OFF_TS + NT + b * 256 + p];
    float m = mask[b * 256 + p];
    __shared__ float cross[4];
    auto bsum = [&](float v) -> float {
        #pragma unroll
        for (int o = 32; o > 0; o >>= 1) v += __shfl_xor(v, o, 64);
        if (lane == 0) cross[wv] = v;
        __syncthreads();
        float r = cross[0] + cross[1] + cross[2] + cross[3];
        __syncthreads();
        return r;
    };
    float msum = bsum(m);
    float sy = bsum(m * (float)h);
    float sx = bsum(m * (float)w);
    msum = fmaxf(msum, 1.0f);
    float cy = sy / msum, cx = sx / msum;
    float dx = (float)w - cx, dy = (float)h - cy;
    float label = expf(-(dx * dx + dy * dy) * 0.125f);   // 2*sigma^2 = 8
    float A = 1.0f, c = 0.0f;
    const float decay = 1.0f - 0.1f * 0.01f;
    #pragma unroll
    for (int it = 0; it < 5; ++it) {
        float resp = A * r0 + c * s0;
        float gc = (1.0f - resp * label > 0.0f) ? (-label * m) : 0.0f;
        float g = bsum(gc) * (1.0f / 256.0f);
        c = decay * c - 0.1f * g;
        A *= decay;
    }
    // output: 4 search pixels per thread
    int g = b * 1024 + p * 4;
    float4 r1 = *(const float4*)(ws + OFF_SR + g);
    float4 r2 = *(const float4*)(ws + OFF_SR + NS + g);
    float4 s1 = *(const float4*)(ws + OFF_SS + g);
    float4 s2 = *(const float4*)(ws + OFF_SS + NS + g);
    const float A5 = 0.99500999000499900f;    // (1 - LR*LAMBDA)^5
    float4 o;
    o.x = A5 * (K1 + r1.x + r2.x) + c * (K2 + s1.x + s2.x);
    o.y = A5 * (K1 + r1.y + r2.y) + c * (K2 + s1.y + s2.y);
    o.z = A5 * (K1 + r1.z + r2.z) + c * (K2 + s1.z + s2.z);
    o.w = A5 * (K1 + r1.w + r2.w) + c * (K2 + s1.w + s2.w);
    *(float4*)(out + g) = o;
}

extern "C" void kernel_launch(void* const* d_in, const int* in_sizes, int n_in,
                              void* d_out, int out_size, void* d_ws, size_t ws_size,
                              hipStream_t stream) {
    const float* sf    = (const float*)d_in[0];  // search_features (32,768,32,32)
    const float* tf    = (const float*)d_in[1];  // target_features (32,768,16,16)
    const float* mask  = (const float*)d_in[2];  // target_mask (32,1,16,16)
    const float* w     = (const float*)d_in[3];  // conv_w (768,768)
    const float* cb    = (const float*)d_in[4];  // conv_b (768)
    const float* gamma = (const float*)d_in[5];
    const float* beta  = (const float*)d_in[6];
    const float* mean  = (const float*)d_in[7];
    const float* var   = (const float*)d_in[8];
    const float* fi    = (const float*)d_in[9];  // filter_init (1,768,1,1)
    float* out = (float*)d_out;
    float* ws  = (float*)d_ws;

    k_prep <<<ECH + 1, 256, 0, stream>>>(w, cb, gamma, beta, mean, var, fi, ws);
    k_prep2<<<6,       256, 0, stream>>>(ws);
    k_dots <<<320,     256, 0, stream>>>(tf, sf, ws);
    k_out  <<<BB,      256, 0, stream>>>(mask, ws, out);
}

// Round 4
// 40.284 us; speedup vs baseline: 1.2451x; 1.2451x over previous
//
#include <hip/hip_runtime.h>
#include <math.h>

#define DD   768
#define BB   32
#define NTP  256        // target pixels per batch (16x16)
#define NSP  1024       // search pixels per batch (32x32)
#define NT   (BB*NTP)   // 8192 target px
#define NS   (BB*NSP)   // 32768 search px
#define ECH  48         // E-chunks for prep
#define CHE  (DD/ECH)   // 16

// ws layout (floats); float4-aligned offsets
#define OFF_UP  0                      // uPart[ECH][DD]
#define OFF_VP  (OFF_UP + ECH*DD)      // vPart[ECH][DD]
#define OFF_U   (OFF_VP + ECH*DD)      // U[DD]
#define OFF_V   (OFF_U + DD)           // V[DD]
#define OFF_K   (OFF_V + DD)           // K1,K2 (+pad)
#define OFF_C5  (OFF_K + 16)           // c5[BB] (+pad)
#define OFF_TR0 (OFF_C5 + 48)          // target R sums [NT]
#define OFF_TS0 (OFF_TR0 + NT)         // target S sums [NT]
// total ~ 91.7K floats ~= 367 KB

#define A5 0.99500999000499900f        // (1 - LR*LAMBDA)^5

__global__ void k_prep(const float* __restrict__ w, const float* __restrict__ cb,
                       const float* __restrict__ gamma, const float* __restrict__ beta,
                       const float* __restrict__ mean, const float* __restrict__ var,
                       const float* __restrict__ fi, float* __restrict__ ws) {
    int bx = blockIdx.x;
    int t = threadIdx.x;
    if (bx < ECH) {
        __shared__ float wu[CHE], wv[CHE];
        if (t < CHE) {
            int e = bx * CHE + t;
            float inv = gamma[e] / sqrtf(var[e] + 1e-5f);
            wv[t] = inv;
            wu[t] = inv * fi[e];
        }
        __syncthreads();
        if (t < 192) {   // 192 float4 = 768 d columns
            const float4* w4 = (const float4*)w;
            float4 Ru = {0,0,0,0}, Rv = {0,0,0,0};
            #pragma unroll
            for (int j = 0; j < CHE; ++j) {
                float4 x = w4[(size_t)(bx * CHE + j) * 192 + t];
                float a = wu[j], b = wv[j];
                Ru.x += x.x * a; Ru.y += x.y * a; Ru.z += x.z * a; Ru.w += x.w * a;
                Rv.x += x.x * b; Rv.y += x.y * b; Rv.z += x.z * b; Rv.w += x.w * b;
            }
            *(float4*)(ws + OFF_UP + bx * DD + t * 4) = Ru;
            *(float4*)(ws + OFF_VP + bx * DD + t * 4) = Rv;
        }
    } else {
        __shared__ float r1[256], r2[256];
        float a1 = 0.f, a2 = 0.f;
        for (int e = t; e < DD; e += 256) {
            float inv = gamma[e] / sqrtf(var[e] + 1e-5f);
            float x = (cb[e] - mean[e]) * inv + beta[e];
            a1 += x * fi[e];
            a2 += x;
        }
        r1[t] = a1; r2[t] = a2;
        __syncthreads();
        for (int s = 128; s > 0; s >>= 1) {
            if (t < s) { r1[t] += r1[t + s]; r2[t] += r2[t + s]; }
            __syncthreads();
        }
        if (t == 0) { ws[OFF_K] = r1[0]; ws[OFF_K + 1] = r2[0]; }
    }
}

__global__ void k_prep2(float* __restrict__ ws) {
    int bx = blockIdx.x;
    int d = (bx % 3) * 256 + threadIdx.x;
    int isV = bx / 3;
    int srcOff = isV ? OFF_VP : OFF_UP;
    int dstOff = isV ? OFF_V : OFF_U;
    float a = 0.f;
    #pragma unroll 8
    for (int ec = 0; ec < ECH; ++ec) a += ws[srcOff + ec * DD + d];
    ws[dstOff + d] = a;
}

// Target dots: 128 blocks; block = 16 f4-px x 16 channel-subs; 48 ch/thread,
// 8-deep explicit pipeline; LDS tree reduce over subs; writes full R,S sums.
__global__ __launch_bounds__(256) void k_dots_t(const float* __restrict__ tf,
                                                float* __restrict__ ws) {
    int t = threadIdx.x;
    int px = t & 15, sub = t >> 4;
    __shared__ float su[DD], sv[DD];
    for (int i = t; i < DD; i += 256) { su[i] = ws[OFF_U + i]; sv[i] = ws[OFF_V + i]; }
    __syncthreads();
    int pf = blockIdx.x * 16 + px;        // target f4-px in [0,2048)
    int b = pf >> 6;
    const float4* base = (const float4*)tf + ((size_t)b * DD + sub * 48) * (NTP/4) + (pf & 63);
    const int STR = NTP / 4;              // 64 f4 per channel row
    float4 accR = {0,0,0,0}, accS = {0,0,0,0};
    float4 buf[8];
    #pragma unroll
    for (int k = 0; k < 8; ++k) buf[k] = base[(size_t)k * STR];
    #pragma unroll
    for (int g = 1; g < 6; ++g) {
        float4 nxt[8];
        #pragma unroll
        for (int k = 0; k < 8; ++k) nxt[k] = base[(size_t)(g * 8 + k) * STR];
        #pragma unroll
        for (int k = 0; k < 8; ++k) {
            int ch = sub * 48 + (g - 1) * 8 + k;
            float u = su[ch], v = sv[ch];
            accR.x += buf[k].x * u; accR.y += buf[k].y * u; accR.z += buf[k].z * u; accR.w += buf[k].w * u;
            accS.x += buf[k].x * v; accS.y += buf[k].y * v; accS.z += buf[k].z * v; accS.w += buf[k].w * v;
            buf[k] = nxt[k];
        }
    }
    #pragma unroll
    for (int k = 0; k < 8; ++k) {
        int ch = sub * 48 + 40 + k;
        float u = su[ch], v = sv[ch];
        accR.x += buf[k].x * u; accR.y += buf[k].y * u; accR.z += buf[k].z * u; accR.w += buf[k].w * u;
        accS.x += buf[k].x * v; accS.y += buf[k].y * v; accS.z += buf[k].z * v; accS.w += buf[k].w * v;
    }
    __shared__ float4 redR[16][16], redS[16][16];
    redR[sub][px] = accR; redS[sub][px] = accS;
    __syncthreads();
    for (int s = 8; s > 0; s >>= 1) {
        if (sub < s) {
            float4 a = redR[sub + s][px], m = redR[sub][px];
            m.x += a.x; m.y += a.y; m.z += a.z; m.w += a.w; redR[sub][px] = m;
            float4 c = redS[sub + s][px], n = redS[sub][px];
            n.x += c.x; n.y += c.y; n.z += c.z; n.w += c.w; redS[sub][px] = n;
        }
        __syncthreads();
    }
    if (sub == 0) {
        ((float4*)(ws + OFF_TR0))[pf] = redR[0][px];
        ((float4*)(ws + OFF_TS0))[pf] = redS[0][px];
    }
}

// Filter iterations per batch -> c5[b]. 32 blocks x 256.
__global__ void k_filter(const float* __restrict__ mask, float* __restrict__ ws) {
    int b = blockIdx.x;
    int p = threadIdx.x;
    int lane = p & 63, wv = p >> 6;
    int h = p >> 4, w = p & 15;
    float K1 = ws[OFF_K], K2 = ws[OFF_K + 1];
    float r0 = K1 + ws[OFF_TR0 + b * 256 + p];
    float s0 = K2 + ws[OFF_TS0 + b * 256 + p];
    float m = mask[b * 256 + p];
    __shared__ float cross[4];
    auto bsum = [&](float v) -> float {
        #pragma unroll
        for (int o = 32; o > 0; o >>= 1) v += __shfl_xor(v, o, 64);
        if (lane == 0) cross[wv] = v;
        __syncthreads();
        float r = cross[0] + cross[1] + cross[2] + cross[3];
        __syncthreads();
        return r;
    };
    float msum = bsum(m);
    float sy = bsum(m * (float)h);
    float sx = bsum(m * (float)w);
    msum = fmaxf(msum, 1.0f);
    float cy = sy / msum, cx = sx / msum;
    float dx = (float)w - cx, dy = (float)h - cy;
    float label = expf(-(dx * dx + dy * dy) * 0.125f);   // 2*sigma^2 = 8
    float A = 1.0f, c = 0.0f;
    const float decay = 1.0f - 0.1f * 0.01f;
    #pragma unroll
    for (int it = 0; it < 5; ++it) {
        float resp = A * r0 + c * s0;
        float gc = (1.0f - resp * label > 0.0f) ? (-label * m) : 0.0f;
        float g = bsum(gc) * (1.0f / 256.0f);
        c = decay * c - 0.1f * g;
        A *= decay;
    }
    if (p == 0) ws[OFF_C5 + b] = c;
}

// Search pass: 512 blocks; block = 16 f4-px x 16 subs; folds A5*U + c5*V into
// one weight vector (1 fma per element), writes FINAL output directly.
__global__ __launch_bounds__(256) void k_out_s(const float* __restrict__ sf,
                                               const float* __restrict__ ws,
                                               float* __restrict__ out) {
    int t = threadIdx.x;
    int px = t & 15, sub = t >> 4;
    int pf = blockIdx.x * 16 + px;        // search f4-px in [0,8192)
    int b = pf >> 8;
    float c5 = ws[OFF_C5 + b];
    float K1 = ws[OFF_K], K2 = ws[OFF_K + 1];
    __shared__ float wc[DD];
    for (int i = t; i < DD; i += 256) wc[i] = A5 * ws[OFF_U + i] + c5 * ws[OFF_V + i];
    __syncthreads();
    const float4* base = (const float4*)sf + ((size_t)b * DD + sub * 48) * (NSP/4) + (pf & 255);
    const int STR = NSP / 4;              // 256 f4 per channel row
    float4 acc = {0,0,0,0};
    float4 buf[8];
    #pragma unroll
    for (int k = 0; k < 8; ++k) buf[k] = base[(size_t)k * STR];
    #pragma unroll
    for (int g = 1; g < 6; ++g) {
        float4 nxt[8];
        #pragma unroll
        for (int k = 0; k < 8; ++k) nxt[k] = base[(size_t)(g * 8 + k) * STR];
        #pragma unroll
        for (int k = 0; k < 8; ++k) {
            float u = wc[sub * 48 + (g - 1) * 8 + k];
            acc.x += buf[k].x * u; acc.y += buf[k].y * u; acc.z += buf[k].z * u; acc.w += buf[k].w * u;
            buf[k] = nxt[k];
        }
    }
    #pragma unroll
    for (int k = 0; k < 8; ++k) {
        float u = wc[sub * 48 + 40 + k];
        acc.x += buf[k].x * u; acc.y += buf[k].y * u; acc.z += buf[k].z * u; acc.w += buf[k].w * u;
    }
    __shared__ float4 red[16][16];
    red[sub][px] = acc;
    __syncthreads();
    for (int s = 8; s > 0; s >>= 1) {
        if (sub < s) {
            float4 a = red[sub + s][px], m = red[sub][px];
            m.x += a.x; m.y += a.y; m.z += a.z; m.w += a.w; red[sub][px] = m;
        }
        __syncthreads();
    }
    if (sub == 0) {
        float4 r = red[0][px];
        float kk = A5 * K1 + c5 * K2;
        r.x += kk; r.y += kk; r.z += kk; r.w += kk;
        ((float4*)out)[pf] = r;
    }
}

extern "C" void kernel_launch(void* const* d_in, const int* in_sizes, int n_in,
                              void* d_out, int out_size, void* d_ws, size_t ws_size,
                              hipStream_t stream) {
    const float* sf    = (const float*)d_in[0];
    const float* tf    = (const float*)d_in[1];
    const float* mask  = (const float*)d_in[2];
    const float* w     = (const float*)d_in[3];
    const float* cb    = (const float*)d_in[4];
    const float* gamma = (const float*)d_in[5];
    const float* beta  = (const float*)d_in[6];
    const float* mean  = (const float*)d_in[7];
    const float* var   = (const float*)d_in[8];
    const float* fi    = (const float*)d_in[9];
    float* out = (float*)d_out;
    float* ws  = (float*)d_ws;

    k_prep  <<<ECH + 1, 256, 0, stream>>>(w, cb, gamma, beta, mean, var, fi, ws);
    k_prep2 <<<6,       256, 0, stream>>>(ws);
    k_dots_t<<<128,     256, 0, stream>>>(tf, ws);
    k_filter<<<BB,      256, 0, stream>>>(mask, ws);
    k_out_s <<<512,     256, 0, stream>>>(sf, ws, out);
}

// Round 5
// 38.337 us; speedup vs baseline: 1.3083x; 1.0508x over previous
//
#include <hip/hip_runtime.h>
#include <math.h>

#define DD   768
#define BB   32
#define NTP  256        // target pixels per batch (16x16)
#define NSP  1024       // search pixels per batch (32x32)
#define NT   (BB*NTP)   // 8192 target px
#define NS   (BB*NSP)   // 32768 search px
#define ECH  48         // E-chunks for prep
#define CHE  (DD/ECH)   // 16

// ws layout (floats); float4-aligned offsets
#define OFF_UP  0                      // uPart[ECH][DD]
#define OFF_VP  (OFF_UP + ECH*DD)      // vPart[ECH][DD]
#define OFF_U   (OFF_VP + ECH*DD)      // U[DD]
#define OFF_V   (OFF_U + DD)           // V[DD]
#define OFF_K   (OFF_V + DD)           // K1,K2 (+pad)
#define OFF_TR0 (OFF_K + 64)           // target R dots [NT]
#define OFF_TS0 (OFF_TR0 + NT)         // target S dots [NT]
#define OFF_SR  (OFF_TS0 + NT)         // search R dots [NS]
#define OFF_SS  (OFF_SR + NS)          // search S dots [NS]
// total ~ 157K floats ~= 630 KB

#define A5 0.99500999000499900f        // (1 - LR*LAMBDA)^5

__global__ void k_prep(const float* __restrict__ w, const float* __restrict__ cb,
                       const float* __restrict__ gamma, const float* __restrict__ beta,
                       const float* __restrict__ mean, const float* __restrict__ var,
                       const float* __restrict__ fi, float* __restrict__ ws) {
    int bx = blockIdx.x;
    int t = threadIdx.x;
    if (bx < ECH) {
        __shared__ float wu[CHE], wv[CHE];
        if (t < CHE) {
            int e = bx * CHE + t;
            float inv = gamma[e] / sqrtf(var[e] + 1e-5f);
            wv[t] = inv;
            wu[t] = inv * fi[e];
        }
        __syncthreads();
        if (t < 192) {   // 192 float4 = 768 d columns
            const float4* w4 = (const float4*)w;
            float4 Ru = {0,0,0,0}, Rv = {0,0,0,0};
            #pragma unroll
            for (int j = 0; j < CHE; ++j) {
                float4 x = w4[(size_t)(bx * CHE + j) * 192 + t];
                float a = wu[j], b = wv[j];
                Ru.x += x.x * a; Ru.y += x.y * a; Ru.z += x.z * a; Ru.w += x.w * a;
                Rv.x += x.x * b; Rv.y += x.y * b; Rv.z += x.z * b; Rv.w += x.w * b;
            }
            *(float4*)(ws + OFF_UP + bx * DD + t * 4) = Ru;
            *(float4*)(ws + OFF_VP + bx * DD + t * 4) = Rv;
        }
    } else {
        __shared__ float r1[256], r2[256];
        float a1 = 0.f, a2 = 0.f;
        for (int e = t; e < DD; e += 256) {
            float inv = gamma[e] / sqrtf(var[e] + 1e-5f);
            float x = (cb[e] - mean[e]) * inv + beta[e];
            a1 += x * fi[e];
            a2 += x;
        }
        r1[t] = a1; r2[t] = a2;
        __syncthreads();
        for (int s = 128; s > 0; s >>= 1) {
            if (t < s) { r1[t] += r1[t + s]; r2[t] += r2[t + s]; }
            __syncthreads();
        }
        if (t == 0) { ws[OFF_K] = r1[0]; ws[OFF_K + 1] = r2[0]; }
    }
}

__global__ void k_prep2(float* __restrict__ ws) {
    int bx = blockIdx.x;
    int d = (bx % 3) * 256 + threadIdx.x;
    int isV = bx / 3;
    int srcOff = isV ? OFF_VP : OFF_UP;
    int dstOff = isV ? OFF_V : OFF_U;
    float a = 0.f;
    #pragma unroll 8
    for (int ec = 0; ec < ECH; ++ec) a += ws[srcOff + ec * DD + d];
    ws[dstOff + d] = a;
}

// One fused pass over BOTH feature tensors: 640 blocks (512 search + 128 target).
// Block = 16 f4-px x 16 channel-subs, 48 ch/thread, 8-deep explicit pipeline,
// computes R (U-dot) and S (V-dot), LDS tree reduce, writes dot pairs.
__global__ __launch_bounds__(256) void k_big(const float* __restrict__ sf,
                                             const float* __restrict__ tf,
                                             float* __restrict__ ws) {
    int bx = blockIdx.x;
    int lb = (bx & 7) * 80 + (bx >> 3);   // XCD-chunked, bijective for 640
    int t = threadIdx.x;
    int px = t & 15, sub = t >> 4;
    __shared__ float su[DD], sv[DD];
    for (int i = t; i < DD; i += 256) { su[i] = ws[OFF_U + i]; sv[i] = ws[OFF_V + i]; }
    __syncthreads();

    const float4* base;
    int STR;
    float4 *oR, *oS;
    if (lb < 512) {
        int pf = lb * 16 + px;            // search f4-px in [0,8192)
        int b = pf >> 8;
        base = (const float4*)sf + ((size_t)b * DD + sub * 48) * (NSP/4) + (pf & 255);
        STR = NSP / 4;
        oR = (float4*)(ws + OFF_SR) + pf;
        oS = (float4*)(ws + OFF_SS) + pf;
    } else {
        int pf = (lb - 512) * 16 + px;    // target f4-px in [0,2048)
        int b = pf >> 6;
        base = (const float4*)tf + ((size_t)b * DD + sub * 48) * (NTP/4) + (pf & 63);
        STR = NTP / 4;
        oR = (float4*)(ws + OFF_TR0) + pf;
        oS = (float4*)(ws + OFF_TS0) + pf;
    }
    float4 accR = {0,0,0,0}, accS = {0,0,0,0};
    float4 buf[8];
    #pragma unroll
    for (int k = 0; k < 8; ++k) buf[k] = base[(size_t)k * STR];
    #pragma unroll
    for (int g = 1; g < 6; ++g) {
        float4 nxt[8];
        #pragma unroll
        for (int k = 0; k < 8; ++k) nxt[k] = base[(size_t)(g * 8 + k) * STR];
        #pragma unroll
        for (int k = 0; k < 8; ++k) {
            int ch = sub * 48 + (g - 1) * 8 + k;
            float u = su[ch], v = sv[ch];
            accR.x += buf[k].x * u; accR.y += buf[k].y * u; accR.z += buf[k].z * u; accR.w += buf[k].w * u;
            accS.x += buf[k].x * v; accS.y += buf[k].y * v; accS.z += buf[k].z * v; accS.w += buf[k].w * v;
            buf[k] = nxt[k];
        }
    }
    #pragma unroll
    for (int k = 0; k < 8; ++k) {
        int ch = sub * 48 + 40 + k;
        float u = su[ch], v = sv[ch];
        accR.x += buf[k].x * u; accR.y += buf[k].y * u; accR.z += buf[k].z * u; accR.w += buf[k].w * u;
        accS.x += buf[k].x * v; accS.y += buf[k].y * v; accS.z += buf[k].z * v; accS.w += buf[k].w * v;
    }
    __shared__ float4 redR[16][16], redS[16][16];
    redR[sub][px] = accR; redS[sub][px] = accS;
    __syncthreads();
    for (int s = 8; s > 0; s >>= 1) {
        if (sub < s) {
            float4 a = redR[sub + s][px], m = redR[sub][px];
            m.x += a.x; m.y += a.y; m.z += a.z; m.w += a.w; redR[sub][px] = m;
            float4 c = redS[sub + s][px], n = redS[sub][px];
            n.x += c.x; n.y += c.y; n.z += c.z; n.w += c.w; redS[sub][px] = n;
        }
        __syncthreads();
    }
    if (sub == 0) { *oR = redR[0][px]; *oS = redS[0][px]; }
}

// Per batch: filter iterations from target dots, then final output combine.
__global__ void k_final(const float* __restrict__ mask, const float* __restrict__ ws,
                        float* __restrict__ out) {
    int b = blockIdx.x;
    int p = threadIdx.x;
    int lane = p & 63, wv = p >> 6;
    int h = p >> 4, w = p & 15;
    float K1 = ws[OFF_K], K2 = ws[OFF_K + 1];
    float r0 = K1 + ws[OFF_TR0 + b * 256 + p];
    float s0 = K2 + ws[OFF_TS0 + b * 256 + p];
    float m = mask[b * 256 + p];
    __shared__ float cross[4];
    auto bsum = [&](float v) -> float {
        #pragma unroll
        for (int o = 32; o > 0; o >>= 1) v += __shfl_xor(v, o, 64);
        if (lane == 0) cross[wv] = v;
        __syncthreads();
        float r = cross[0] + cross[1] + cross[2] + cross[3];
        __syncthreads();
        return r;
    };
    float msum = bsum(m);
    float sy = bsum(m * (float)h);
    float sx = bsum(m * (float)w);
    msum = fmaxf(msum, 1.0f);
    float cy = sy / msum, cx = sx / msum;
    float dx = (float)w - cx, dy = (float)h - cy;
    float label = expf(-(dx * dx + dy * dy) * 0.125f);   // 2*sigma^2 = 8
    float A = 1.0f, c = 0.0f;
    const float decay = 1.0f - 0.1f * 0.01f;
    #pragma unroll
    for (int it = 0; it < 5; ++it) {
        float resp = A * r0 + c * s0;
        float gc = (1.0f - resp * label > 0.0f) ? (-label * m) : 0.0f;
        float g = bsum(gc) * (1.0f / 256.0f);
        c = decay * c - 0.1f * g;
        A *= decay;
    }
    // combine: 4 search px per thread
    int g4 = b * 256 + p;                 // f4 index
    float4 R = ((const float4*)(ws + OFF_SR))[g4];
    float4 S = ((const float4*)(ws + OFF_SS))[g4];
    float4 o;
    o.x = A5 * (K1 + R.x) + c * (K2 + S.x);
    o.y = A5 * (K1 + R.y) + c * (K2 + S.y);
    o.z = A5 * (K1 + R.z) + c * (K2 + S.z);
    o.w = A5 * (K1 + R.w) + c * (K2 + S.w);
    ((float4*)out)[g4] = o;
}

extern "C" void kernel_launch(void* const* d_in, const int* in_sizes, int n_in,
                              void* d_out, int out_size, void* d_ws, size_t ws_size,
                              hipStream_t stream) {
    const float* sf    = (const float*)d_in[0];
    const float* tf    = (const float*)d_in[1];
    const float* mask  = (const float*)d_in[2];
    const float* w     = (const float*)d_in[3];
    const float* cb    = (const float*)d_in[4];
    const float* gamma = (const float*)d_in[5];
    const float* beta  = (const float*)d_in[6];
    const float* mean  = (const float*)d_in[7];
    const float* var   = (const float*)d_in[8];
    const float* fi    = (const float*)d_in[9];
    float* out = (float*)d_out;
    float* ws  = (float*)d_ws;

    k_prep <<<ECH + 1, 256, 0, stream>>>(w, cb, gamma, beta, mean, var, fi, ws);
    k_prep2<<<6,       256, 0, stream>>>(ws);
    k_big  <<<640,     256, 0, stream>>>(sf, tf, ws);
    k_final<<<BB,      256, 0, stream>>>(mask, ws, out);
}

// Round 6
// 35.922 us; speedup vs baseline: 1.3963x; 1.0672x over previous
//
#include <hip/hip_runtime.h>
#include <math.h>

#define DD   768
#define BB   32
#define NTP  256        // target pixels per batch (16x16)
#define NSP  1024       // search pixels per batch (32x32)
#define NT   (BB*NTP)   // 8192 target px
#define NS   (BB*NSP)   // 32768 search px
#define ECH  16         // E-chunks for prep (48 rows each)
#define CHE  (DD/ECH)   // 48

// ws layout (floats); float4-aligned offsets
#define OFF_UP  0                      // uPart[ECH][DD]
#define OFF_VP  (OFF_UP + ECH*DD)      // vPart[ECH][DD]
#define OFF_K   (OFF_VP + ECH*DD)      // K1,K2 (+pad)
#define OFF_TR0 (OFF_K + 64)           // target R dots [NT] (f4 layout)
#define OFF_TS0 (OFF_TR0 + NT)         // target S dots [NT]
#define OFF_SR  (OFF_TS0 + NT)         // search R dots [NS]
#define OFF_SS  (OFF_SR + NS)          // search S dots [NS]

#define A5 0.99500999000499900f        // (1 - LR*LAMBDA)^5

// 17 blocks: 16 compute U/V partials over 48-row chunks of w; 1 computes K1/K2.
__global__ void k_prep(const float* __restrict__ w, const float* __restrict__ cb,
                       const float* __restrict__ gamma, const float* __restrict__ beta,
                       const float* __restrict__ mean, const float* __restrict__ var,
                       const float* __restrict__ fi, float* __restrict__ ws) {
    int bx = blockIdx.x;
    int t = threadIdx.x;
    if (bx < ECH) {
        __shared__ float wu[CHE], wv[CHE];
        if (t < CHE) {
            int e = bx * CHE + t;
            float inv = gamma[e] / sqrtf(var[e] + 1e-5f);
            wv[t] = inv;
            wu[t] = inv * fi[e];
        }
        __syncthreads();
        if (t < 192) {   // one f4-column (4 d's) per thread
            const float4* w4 = (const float4*)w;
            float4 Ru = {0,0,0,0}, Rv = {0,0,0,0};
            #pragma unroll
            for (int j = 0; j < CHE; ++j) {
                float4 x = w4[(size_t)(bx * CHE + j) * 192 + t];
                float a = wu[j], b = wv[j];
                Ru.x += x.x * a; Ru.y += x.y * a; Ru.z += x.z * a; Ru.w += x.w * a;
                Rv.x += x.x * b; Rv.y += x.y * b; Rv.z += x.z * b; Rv.w += x.w * b;
            }
            *(float4*)(ws + OFF_UP + bx * DD + t * 4) = Ru;
            *(float4*)(ws + OFF_VP + bx * DD + t * 4) = Rv;
        }
    } else {
        __shared__ float r1[256], r2[256];
        float a1 = 0.f, a2 = 0.f;
        for (int e = t; e < DD; e += 256) {
            float inv = gamma[e] / sqrtf(var[e] + 1e-5f);
            float x = (cb[e] - mean[e]) * inv + beta[e];
            a1 += x * fi[e];
            a2 += x;
        }
        r1[t] = a1; r2[t] = a2;
        __syncthreads();
        for (int s = 128; s > 0; s >>= 1) {
            if (t < s) { r1[t] += r1[t + s]; r2[t] += r2[t + s]; }
            __syncthreads();
        }
        if (t == 0) { ws[OFF_K] = r1[0]; ws[OFF_K + 1] = r2[0]; }
    }
}

// 320 balanced blocks: 256 search (32 batches x 8 px-groups of 128px) +
// 64 target (32 batches x 2 px-groups of 128px). Each block covers ALL 768
// channels (8 subs x 96 ch) for its 128 px -> complete dots, no partials.
// Wave loads are 512B-contiguous; 12-deep explicit pipeline (8 groups of 12).
// Each block first self-reduces U/V from the 16 prep partials (L2/L3-hot).
__global__ __launch_bounds__(256) void k_big(const float* __restrict__ sf,
                                             const float* __restrict__ tf,
                                             float* __restrict__ ws) {
    int bx = blockIdx.x;
    int t = threadIdx.x;
    int pxf4 = t & 31, sub = t >> 5;      // 32 f4-px, 8 channel-subs
    __shared__ float su[DD], sv[DD];
    if (t < 192) {
        float4 U = {0,0,0,0}, V = {0,0,0,0};
        #pragma unroll
        for (int ec = 0; ec < ECH; ++ec) {
            float4 a = ((const float4*)(ws + OFF_UP + ec * DD))[t];
            float4 b = ((const float4*)(ws + OFF_VP + ec * DD))[t];
            U.x += a.x; U.y += a.y; U.z += a.z; U.w += a.w;
            V.x += b.x; V.y += b.y; V.z += b.z; V.w += b.w;
        }
        ((float4*)su)[t] = U;
        ((float4*)sv)[t] = V;
    }
    __syncthreads();

    const float4* base;
    int STR;
    float4 *oR, *oS;
    if (bx < 256) {
        int b = bx >> 3, q = bx & 7;      // 8 groups of 128 px
        base = (const float4*)sf + ((size_t)b * DD + sub * 96) * (NSP/4) + q * 32 + pxf4;
        STR = NSP / 4;                    // 256
        int g4 = b * 256 + q * 32 + pxf4;
        oR = (float4*)(ws + OFF_SR) + g4;
        oS = (float4*)(ws + OFF_SS) + g4;
    } else {
        int u = bx - 256;
        int b = u >> 1, q = u & 1;        // 2 groups of 128 px
        base = (const float4*)tf + ((size_t)b * DD + sub * 96) * (NTP/4) + q * 32 + pxf4;
        STR = NTP / 4;                    // 64
        int g4 = b * 64 + q * 32 + pxf4;
        oR = (float4*)(ws + OFF_TR0) + g4;
        oS = (float4*)(ws + OFF_TS0) + g4;
    }

    float4 accR = {0,0,0,0}, accS = {0,0,0,0};
    float4 buf[12];
    #pragma unroll
    for (int k = 0; k < 12; ++k) buf[k] = base[(size_t)k * STR];
    #pragma unroll
    for (int g = 1; g < 8; ++g) {
        float4 nxt[12];
        #pragma unroll
        for (int k = 0; k < 12; ++k) nxt[k] = base[(size_t)(g * 12 + k) * STR];
        #pragma unroll
        for (int k = 0; k < 12; ++k) {
            int ch = sub * 96 + (g - 1) * 12 + k;
            float u = su[ch], v = sv[ch];
            accR.x += buf[k].x * u; accR.y += buf[k].y * u; accR.z += buf[k].z * u; accR.w += buf[k].w * u;
            accS.x += buf[k].x * v; accS.y += buf[k].y * v; accS.z += buf[k].z * v; accS.w += buf[k].w * v;
            buf[k] = nxt[k];
        }
    }
    #pragma unroll
    for (int k = 0; k < 12; ++k) {
        int ch = sub * 96 + 84 + k;
        float u = su[ch], v = sv[ch];
        accR.x += buf[k].x * u; accR.y += buf[k].y * u; accR.z += buf[k].z * u; accR.w += buf[k].w * u;
        accS.x += buf[k].x * v; accS.y += buf[k].y * v; accS.z += buf[k].z * v; accS.w += buf[k].w * v;
    }

    __shared__ float4 redR[8][32], redS[8][32];
    redR[sub][pxf4] = accR; redS[sub][pxf4] = accS;
    __syncthreads();
    for (int s = 4; s > 0; s >>= 1) {
        if (sub < s) {
            float4 a = redR[sub + s][pxf4], m = redR[sub][pxf4];
            m.x += a.x; m.y += a.y; m.z += a.z; m.w += a.w; redR[sub][pxf4] = m;
            float4 c = redS[sub + s][pxf4], n = redS[sub][pxf4];
            n.x += c.x; n.y += c.y; n.z += c.z; n.w += c.w; redS[sub][pxf4] = n;
        }
        __syncthreads();
    }
    if (sub == 0) { *oR = redR[0][pxf4]; *oS = redS[0][pxf4]; }
}

// Per batch: filter iterations from target dots, then final output combine.
__global__ void k_final(const float* __restrict__ mask, const float* __restrict__ ws,
                        float* __restrict__ out) {
    int b = blockIdx.x;
    int p = threadIdx.x;
    int lane = p & 63, wv = p >> 6;
    int h = p >> 4, w = p & 15;
    float K1 = ws[OFF_K], K2 = ws[OFF_K + 1];
    float r0 = K1 + ws[OFF_TR0 + b * 256 + p];
    float s0 = K2 + ws[OFF_TS0 + b * 256 + p];
    float m = mask[b * 256 + p];
    __shared__ float cross[4];
    auto bsum = [&](float v) -> float {
        #pragma unroll
        for (int o = 32; o > 0; o >>= 1) v += __shfl_xor(v, o, 64);
        if (lane == 0) cross[wv] = v;
        __syncthreads();
        float r = cross[0] + cross[1] + cross[2] + cross[3];
        __syncthreads();
        return r;
    };
    float msum = bsum(m);
    float sy = bsum(m * (float)h);
    float sx = bsum(m * (float)w);
    msum = fmaxf(msum, 1.0f);
    float cy = sy / msum, cx = sx / msum;
    float dx = (float)w - cx, dy = (float)h - cy;
    float label = expf(-(dx * dx + dy * dy) * 0.125f);   // 2*sigma^2 = 8
    float A = 1.0f, c = 0.0f;
    const float decay = 1.0f - 0.1f * 0.01f;
    #pragma unroll
    for (int it = 0; it < 5; ++it) {
        float resp = A * r0 + c * s0;
        float gc = (1.0f - resp * label > 0.0f) ? (-label * m) : 0.0f;
        float g = bsum(gc) * (1.0f / 256.0f);
        c = decay * c - 0.1f * g;
        A *= decay;
    }
    // combine: 4 search px per thread
    int g4 = b * 256 + p;                 // f4 index
    float4 R = ((const float4*)(ws + OFF_SR))[g4];
    float4 S = ((const float4*)(ws + OFF_SS))[g4];
    float4 o;
    o.x = A5 * (K1 + R.x) + c * (K2 + S.x);
    o.y = A5 * (K1 + R.y) + c * (K2 + S.y);
    o.z = A5 * (K1 + R.z) + c * (K2 + S.z);
    o.w = A5 * (K1 + R.w) + c * (K2 + S.w);
    ((float4*)out)[g4] = o;
}

extern "C" void kernel_launch(void* const* d_in, const int* in_sizes, int n_in,
                              void* d_out, int out_size, void* d_ws, size_t ws_size,
                              hipStream_t stream) {
    const float* sf    = (const float*)d_in[0];
    const float* tf    = (const float*)d_in[1];
    const float* mask  = (const float*)d_in[2];
    const float* w     = (const float*)d_in[3];
    const float* cb    = (const float*)d_in[4];
    const float* gamma = (const float*)d_in[5];
    const float* beta  = (const float*)d_in[6];
    const float* mean  = (const float*)d_in[7];
    const float* var   = (const float*)d_in[8];
    const float* fi    = (const float*)d_in[9];
    float* out = (float*)d_out;
    float* ws  = (float*)d_ws;

    k_prep <<<ECH + 1, 256, 0, stream>>>(w, cb, gamma, beta, mean, var, fi, ws);
    k_big  <<<320,     256, 0, stream>>>(sf, tf, ws);
    k_final<<<BB,      256, 0, stream>>>(mask, ws, out);
}

// Round 7
// 34.612 us; speedup vs baseline: 1.4491x; 1.0378x over previous
//
#include <hip/hip_runtime.h>
#include <math.h>

#define DD   768
#define BB   32
#define NTP  256        // target pixels per batch (16x16)
#define NSP  1024       // search pixels per batch (32x32)
#define NT   (BB*NTP)   // 8192 target px
#define NS   (BB*NSP)   // 32768 search px
#define ECH  16         // E-chunks for prep (48 rows each)
#define CHE  (DD/ECH)   // 48
#define NQ   4          // channel quarters
#define QCH  (DD/NQ)    // 192

// ws layout (floats); float4-aligned offsets
#define OFF_UP  0                      // uPart[ECH][DD]
#define OFF_VP  (OFF_UP + ECH*DD)      // vPart[ECH][DD]
#define OFF_K   (OFF_VP + ECH*DD)      // K1,K2 (+pad)
#define OFF_TR0 (OFF_K + 64)           // target R dots [NQ][NT]
#define OFF_TS0 (OFF_TR0 + NQ*NT)      // target S dots [NQ][NT]
#define OFF_SR  (OFF_TS0 + NQ*NT)      // search R dots [NQ][NS]
#define OFF_SS  (OFF_SR + NQ*NS)       // search S dots [NQ][NS]
// total ~ 352K floats ~= 1.4 MB

#define A5 0.99500999000499900f        // (1 - LR*LAMBDA)^5

// 17 blocks: 16 compute U/V partials over 48-row chunks of w; 1 computes K1/K2.
__global__ void k_prep(const float* __restrict__ w, const float* __restrict__ cb,
                       const float* __restrict__ gamma, const float* __restrict__ beta,
                       const float* __restrict__ mean, const float* __restrict__ var,
                       const float* __restrict__ fi, float* __restrict__ ws) {
    int bx = blockIdx.x;
    int t = threadIdx.x;
    if (bx < ECH) {
        __shared__ float wu[CHE], wv[CHE];
        if (t < CHE) {
            int e = bx * CHE + t;
            float inv = gamma[e] / sqrtf(var[e] + 1e-5f);
            wv[t] = inv;
            wu[t] = inv * fi[e];
        }
        __syncthreads();
        if (t < 192) {   // one f4-column (4 d's) per thread
            const float4* w4 = (const float4*)w;
            float4 Ru = {0,0,0,0}, Rv = {0,0,0,0};
            #pragma unroll
            for (int j = 0; j < CHE; ++j) {
                float4 x = w4[(size_t)(bx * CHE + j) * 192 + t];
                float a = wu[j], b = wv[j];
                Ru.x += x.x * a; Ru.y += x.y * a; Ru.z += x.z * a; Ru.w += x.w * a;
                Rv.x += x.x * b; Rv.y += x.y * b; Rv.z += x.z * b; Rv.w += x.w * b;
            }
            *(float4*)(ws + OFF_UP + bx * DD + t * 4) = Ru;
            *(float4*)(ws + OFF_VP + bx * DD + t * 4) = Rv;
        }
    } else {
        __shared__ float r1[256], r2[256];
        float a1 = 0.f, a2 = 0.f;
        for (int e = t; e < DD; e += 256) {
            float inv = gamma[e] / sqrtf(var[e] + 1e-5f);
            float x = (cb[e] - mean[e]) * inv + beta[e];
            a1 += x * fi[e];
            a2 += x;
        }
        r1[t] = a1; r2[t] = a2;
        __syncthreads();
        for (int s = 128; s > 0; s >>= 1) {
            if (t < s) { r1[t] += r1[t + s]; r2[t] += r2[t + s]; }
            __syncthreads();
        }
        if (t == 0) { ws[OFF_K] = r1[0]; ws[OFF_K + 1] = r2[0]; }
    }
}

// 1280 identical blocks = exactly 5/CU.
//   search: 1024 = 32 batches x 8 px-groups(128px) x 4 ch-quarters(192ch)
//   target:  256 = 32 batches x 2 px-groups(128px) x 4 ch-quarters
// Block = 32 f4-px x 8 subs; 24 ch/thread; 8-deep explicit pipeline.
// Prologue self-reduces this block's 192-ch U/V slice from prep partials.
__global__ __launch_bounds__(256, 5) void k_big(const float* __restrict__ sf,
                                                const float* __restrict__ tf,
                                                float* __restrict__ ws) {
    int bx = blockIdx.x;
    int t = threadIdx.x;
    int pxf4 = t & 31, sub = t >> 5;      // 32 f4-px, 8 channel-subs (24 ch each)

    int b, q, cq; bool isS;
    if (bx < 1024) { isS = true;  cq = bx & 3; q = (bx >> 2) & 7; b = bx >> 5; }
    else           { isS = false; int u = bx - 1024; cq = u & 3; q = (u >> 2) & 1; b = u >> 3; }

    __shared__ float su[QCH], sv[QCH];
    if (t < QCH / 4) {                    // 48 threads, one f4 each
        float4 U = {0,0,0,0}, V = {0,0,0,0};
        #pragma unroll
        for (int ec = 0; ec < ECH; ++ec) {
            float4 a = ((const float4*)(ws + OFF_UP))[ec * 192 + cq * 48 + t];
            float4 c = ((const float4*)(ws + OFF_VP))[ec * 192 + cq * 48 + t];
            U.x += a.x; U.y += a.y; U.z += a.z; U.w += a.w;
            V.x += c.x; V.y += c.y; V.z += c.z; V.w += c.w;
        }
        ((float4*)su)[t] = U;
        ((float4*)sv)[t] = V;
    }
    __syncthreads();

    const float4* base;
    int STR;
    float4 *oR, *oS;
    if (isS) {
        base = (const float4*)sf + ((size_t)b * DD + cq * QCH + sub * 24) * (NSP/4) + q * 32 + pxf4;
        STR = NSP / 4;                    // 256
        int g4 = b * 256 + q * 32 + pxf4;
        oR = (float4*)(ws + OFF_SR) + cq * (NS/4) + g4;
        oS = (float4*)(ws + OFF_SS) + cq * (NS/4) + g4;
    } else {
        base = (const float4*)tf + ((size_t)b * DD + cq * QCH + sub * 24) * (NTP/4) + q * 32 + pxf4;
        STR = NTP / 4;                    // 64
        int g4 = b * 64 + q * 32 + pxf4;
        oR = (float4*)(ws + OFF_TR0) + cq * (NT/4) + g4;
        oS = (float4*)(ws + OFF_TS0) + cq * (NT/4) + g4;
    }

    float4 accR = {0,0,0,0}, accS = {0,0,0,0};
    float4 buf[8];
    #pragma unroll
    for (int k = 0; k < 8; ++k) buf[k] = base[(size_t)k * STR];
    #pragma unroll
    for (int g = 1; g < 3; ++g) {
        float4 nxt[8];
        #pragma unroll
        for (int k = 0; k < 8; ++k) nxt[k] = base[(size_t)(g * 8 + k) * STR];
        #pragma unroll
        for (int k = 0; k < 8; ++k) {
            int ch = sub * 24 + (g - 1) * 8 + k;
            float u = su[ch], v = sv[ch];
            accR.x += buf[k].x * u; accR.y += buf[k].y * u; accR.z += buf[k].z * u; accR.w += buf[k].w * u;
            accS.x += buf[k].x * v; accS.y += buf[k].y * v; accS.z += buf[k].z * v; accS.w += buf[k].w * v;
            buf[k] = nxt[k];
        }
    }
    #pragma unroll
    for (int k = 0; k < 8; ++k) {
        int ch = sub * 24 + 16 + k;
        float u = su[ch], v = sv[ch];
        accR.x += buf[k].x * u; accR.y += buf[k].y * u; accR.z += buf[k].z * u; accR.w += buf[k].w * u;
        accS.x += buf[k].x * v; accS.y += buf[k].y * v; accS.z += buf[k].z * v; accS.w += buf[k].w * v;
    }

    __shared__ float4 redR[8][32], redS[8][32];
    redR[sub][pxf4] = accR; redS[sub][pxf4] = accS;
    __syncthreads();
    for (int s = 4; s > 0; s >>= 1) {
        if (sub < s) {
            float4 a = redR[sub + s][pxf4], m = redR[sub][pxf4];
            m.x += a.x; m.y += a.y; m.z += a.z; m.w += a.w; redR[sub][pxf4] = m;
            float4 c = redS[sub + s][pxf4], n = redS[sub][pxf4];
            n.x += c.x; n.y += c.y; n.z += c.z; n.w += c.w; redS[sub][pxf4] = n;
        }
        __syncthreads();
    }
    if (sub == 0) { *oR = redR[0][pxf4]; *oS = redS[0][pxf4]; }
}

// Per batch: filter iterations from target dots (sum of 4 quarter partials),
// then final output combine (4 search px per thread).
__global__ void k_final(const float* __restrict__ mask, const float* __restrict__ ws,
                        float* __restrict__ out) {
    int b = blockIdx.x;
    int p = threadIdx.x;
    int lane = p & 63, wv = p >> 6;
    int h = p >> 4, w = p & 15;
    float K1 = ws[OFF_K], K2 = ws[OFF_K + 1];
    float r0 = K1, s0 = K2;
    #pragma unroll
    for (int cq = 0; cq < NQ; ++cq) {
        r0 += ws[OFF_TR0 + cq * NT + b * 256 + p];
        s0 += ws[OFF_TS0 + cq * NT + b * 256 + p];
    }
    float m = mask[b * 256 + p];
    __shared__ float cross[4];
    auto bsum = [&](float v) -> float {
        #pragma unroll
        for (int o = 32; o > 0; o >>= 1) v += __shfl_xor(v, o, 64);
        if (lane == 0) cross[wv] = v;
        __syncthreads();
        float r = cross[0] + cross[1] + cross[2] + cross[3];
        __syncthreads();
        return r;
    };
    float msum = bsum(m);
    float sy = bsum(m * (float)h);
    float sx = bsum(m * (float)w);
    msum = fmaxf(msum, 1.0f);
    float cy = sy / msum, cx = sx / msum;
    float dx = (float)w - cx, dy = (float)h - cy;
    float label = expf(-(dx * dx + dy * dy) * 0.125f);   // 2*sigma^2 = 8
    float A = 1.0f, c = 0.0f;
    const float decay = 1.0f - 0.1f * 0.01f;
    #pragma unroll
    for (int it = 0; it < 5; ++it) {
        float resp = A * r0 + c * s0;
        float gc = (1.0f - resp * label > 0.0f) ? (-label * m) : 0.0f;
        float g = bsum(gc) * (1.0f / 256.0f);
        c = decay * c - 0.1f * g;
        A *= decay;
    }
    // combine: 4 search px per thread
    int g4 = b * 256 + p;                 // f4 index into [NS/4]
    float4 R = {K1, K1, K1, K1}, S = {K2, K2, K2, K2};
    #pragma unroll
    for (int cq = 0; cq < NQ; ++cq) {
        float4 a = ((const float4*)(ws + OFF_SR))[cq * (NS/4) + g4];
        float4 d = ((const float4*)(ws + OFF_SS))[cq * (NS/4) + g4];
        R.x += a.x; R.y += a.y; R.z += a.z; R.w += a.w;
        S.x += d.x; S.y += d.y; S.z += d.z; S.w += d.w;
    }
    float4 o;
    o.x = A5 * R.x + c * S.x;
    o.y = A5 * R.y + c * S.y;
    o.z = A5 * R.z + c * S.z;
    o.w = A5 * R.w + c * S.w;
    ((float4*)out)[g4] = o;
}

extern "C" void kernel_launch(void* const* d_in, const int* in_sizes, int n_in,
                              void* d_out, int out_size, void* d_ws, size_t ws_size,
                              hipStream_t stream) {
    const float* sf    = (const float*)d_in[0];
    const float* tf    = (const float*)d_in[1];
    const float* mask  = (const float*)d_in[2];
    const float* w     = (const float*)d_in[3];
    const float* cb    = (const float*)d_in[4];
    const float* gamma = (const float*)d_in[5];
    const float* beta  = (const float*)d_in[6];
    const float* mean  = (const float*)d_in[7];
    const float* var   = (const float*)d_in[8];
    const float* fi    = (const float*)d_in[9];
    float* out = (float*)d_out;
    float* ws  = (float*)d_ws;

    k_prep <<<ECH + 1, 256, 0, stream>>>(w, cb, gamma, beta, mean, var, fi, ws);
    k_big  <<<1280,    256, 0, stream>>>(sf, tf, ws);
    k_final<<<BB,      256, 0, stream>>>(mask, ws, out);
}